// Round 3
// baseline (1307.493 us; speedup 1.0000x reference)
//
#include <hip/hip_runtime.h>
#include <math.h>

#define N_NODES 2048
#define NN64 (N_NODES*64)
#define NET 3
#define NE 65536
#define TE 196608
#define W_IN 256
#define NTGT 512
#define GB 512
#define NTHR 256
#define HB 16
#define RFL(x) __builtin_amdgcn_readfirstlane(x)

// workspace float offsets
#define OFF_BAR   0
#define OFF_FILT  16
#define OFF_RS    32
#define OFF_CUR   2096
#define OFF_PART  4144
#define OFF_ECOL  36912
#define OFF_EV    233520
#define OFF_XP    1019952
#define OFF_H1    1282096
#define OFF_H2    1544240
#define OFF_S0    1806384
#define OFF_S1    1810480
#define OFF_DINV  1814576
#define OFF_M1D   1816624
#define OFF_U     1849392
#define OFF_M2D   1914928
#define OFF_V     2046000
#define OFF_HOUT  2308144

__device__ __forceinline__ void gbar(int* cnt) {
    __syncthreads();
    __threadfence();
    if (threadIdx.x == 0) {
        atomicAdd(cnt, 1);
        while (__hip_atomic_load(cnt, __ATOMIC_RELAXED, __HIP_MEMORY_SCOPE_AGENT) < GB)
            __builtin_amdgcn_s_sleep(2);
    }
    __syncthreads();
    __threadfence();
}

__global__ __launch_bounds__(NTHR, 2) void k_mega(
    const float* __restrict__ X, const float* __restrict__ edge_value,
    const float* __restrict__ conv_w, const float* __restrict__ Ws,
    const float* __restrict__ w1, const float* __restrict__ b1,
    const float* __restrict__ w2, const float* __restrict__ b2,
    const float* __restrict__ lin_w, const float* __restrict__ lin_b,
    const int* __restrict__ ei, const int* __restrict__ tgt,
    float* __restrict__ out, float* __restrict__ ws)
{
    __shared__ int lh[2048];
    const int b = blockIdx.x, tid = threadIdx.x;
    const int lane = tid & 63;
    const int W = RFL(b*4 + (tid >> 6));          // wave id 0..2047

    int*    bar       = (int*)(ws + OFF_BAR);
    float*  filt      = ws + OFF_FILT;
    int*    row_start = (int*)(ws + OFF_RS);
    int*    cursor    = (int*)(ws + OFF_CUR);
    int*    part      = (int*)(ws + OFF_PART);
    int*    ecol      = (int*)(ws + OFF_ECOL);
    float*  evbuf     = ws + OFF_EV;
    float4* ev4       = (float4*)evbuf;
    const float2* ev2 = (const float2*)evbuf;
    float*  Xp   = ws + OFF_XP;
    float*  H1   = ws + OFF_H1;
    float*  H2   = ws + OFF_H2;
    float*  s0   = ws + OFF_S0;
    float*  s1   = ws + OFF_S1;
    float*  dinv = ws + OFF_DINV;
    float*  M1d  = ws + OFF_M1D;
    float*  U    = ws + OFF_U;
    float*  M2d  = ws + OFF_M2D;
    float*  V    = ws + OFF_V;
    float*  hout = ws + OFF_HOUT;

    // ---------------- P0: LDS-partial histogram (blocks<HB) + filt + projection ----------------
    if (b < HB) {
        for (int k = tid; k < 2048; k += NTHR) lh[k] = 0;
        __syncthreads();
        const int per = TE / HB;
        for (int e = b*per + tid; e < (b+1)*per; e += NTHR) {
            int t = e >> 16, idx = e & 0xFFFF;
            atomicAdd(&lh[ei[t*2*NE + idx]], 1);
        }
        __syncthreads();
        for (int k = tid; k < 2048; k += NTHR) part[b*2048 + k] = lh[k];
    }
    if (b == 0 && tid < 4) {
        float a = conv_w[tid*3+0], bb = conv_w[tid*3+1], cc = conv_w[tid*3+2];
        float m = fmaxf(a, fmaxf(bb, cc));
        float ea = expf(a-m), eb = expf(bb-m), ec = expf(cc-m);
        float s = ea + eb + ec;
        filt[tid*3+0] = ea/s; filt[tid*3+1] = eb/s; filt[tid*3+2] = ec/s;
    }
    for (int g = b*NTHR + tid; g < 2*NN64; g += GB*NTHR) {
        int d = g & 63;
        int n = (g >> 6) & (N_NODES - 1);
        int c = g >> 17;
        const float* xr = X + n*W_IN;
        const float* wc = Ws + c*(W_IN*64) + d;
        float a0=0.f, a1=0.f, a2=0.f, a3=0.f;
        for (int f = 0; f < W_IN; f += 4) {
            a0 += xr[f+0] * wc[(f+0)*64];
            a1 += xr[f+1] * wc[(f+1)*64];
            a2 += xr[f+2] * wc[(f+2)*64];
            a3 += xr[f+3] * wc[(f+3)*64];
        }
        Xp[g] = (a0+a1) + (a2+a3);
    }
    gbar(&bar[0]);

    // ---------------- P1: scan (block 0) ----------------
    if (b == 0) {
        int loc[8]; int s = 0;
        #pragma unroll
        for (int k = 0; k < 8; k++) {
            int row = tid*8 + k;
            int c = 0;
            #pragma unroll
            for (int hb = 0; hb < HB; hb++) c += part[hb*2048 + row];
            loc[k] = s; s += c;
        }
        lh[tid] = s;
        __syncthreads();
        for (int off = 1; off < 256; off <<= 1) {
            int v = (tid >= off) ? lh[tid - off] : 0;
            __syncthreads();
            lh[tid] += v;
            __syncthreads();
        }
        int basep = tid ? lh[tid-1] : 0;
        #pragma unroll
        for (int k = 0; k < 8; k++) {
            int rs0 = basep + loc[k];
            row_start[tid*8 + k] = rs0;
            cursor[tid*8 + k] = rs0;
        }
        if (tid == 255) row_start[N_NODES] = lh[255];
    }
    gbar(&bar[1]);

    // ---------------- P2: build CSR with pre-scaled edge values ----------------
    {
        float fl[12];
        #pragma unroll
        for (int k = 0; k < 12; k++) fl[k] = filt[k];
        for (int e = b*NTHR + tid; e < TE; e += GB*NTHR) {
            int t = e >> 16, idx = e & 0xFFFF;
            int row = ei[t*2*NE + idx];
            int col = ei[t*2*NE + NE + idx];
            float ev = edge_value[e];
            int pos = atomicAdd(&cursor[row], 1);
            float f00 = (t==0)?fl[0]:((t==1)?fl[1]:fl[2]);
            float f01 = (t==0)?fl[3]:((t==1)?fl[4]:fl[5]);
            float f10 = (t==0)?fl[6]:((t==1)?fl[7]:fl[8]);
            float f11 = (t==0)?fl[9]:((t==1)?fl[10]:fl[11]);
            ecol[pos] = col;
            ev4[pos] = make_float4(ev*f00, ev*f01, ev*f10, ev*f11);
        }
    }
    gbar(&bar[2]);

    // ---------------- P3: H1 = mats_l0 @ Xp (both channels), s0 = rowsum ----------------
    {
        int r = W;
        int begin = row_start[r], end = row_start[r+1];
        float a0=0.f,a1=0.f,p0=0.f,p1=0.f, vs0=0.f, vs1=0.f;
        int j = begin;
        for (; j+2 <= end; j += 2) {
            int cA = ecol[j], cB = ecol[j+1];
            float2 eA = ev2[2*j], eB = ev2[2*j+2];
            a0 += eA.x * Xp[cA*64 + lane];
            p0 += eA.y * Xp[NN64 + cA*64 + lane];
            a1 += eB.x * Xp[cB*64 + lane];
            p1 += eB.y * Xp[NN64 + cB*64 + lane];
            vs0 += eA.x + eB.x; vs1 += eA.y + eB.y;
        }
        if (j < end) {
            int cA = ecol[j]; float2 eA = ev2[2*j];
            a0 += eA.x * Xp[cA*64 + lane];
            p0 += eA.y * Xp[NN64 + cA*64 + lane];
            vs0 += eA.x; vs1 += eA.y;
        }
        H1[r*64 + lane] = a0 + a1;
        H1[NN64 + r*64 + lane] = p0 + p1;
        if (lane == 0) { s0[r] = vs0; s0[N_NODES + r] = vs1; }
    }
    gbar(&bar[3]);

    // ---------------- P4: H2 = mats_l1 @ H1, s1 = mats_l1 @ s0 ----------------
    {
        int r = W;
        int begin = row_start[r], end = row_start[r+1];
        float a0=0.f,a1=0.f,p0=0.f,p1=0.f, sv0=0.f, sv1=0.f;
        int j = begin;
        for (; j+2 <= end; j += 2) {
            int cA = ecol[j], cB = ecol[j+1];
            float2 eA = ev2[2*j+1], eB = ev2[2*j+3];
            a0 += eA.x * H1[cA*64 + lane];
            p0 += eA.y * H1[NN64 + cA*64 + lane];
            a1 += eB.x * H1[cB*64 + lane];
            p1 += eB.y * H1[NN64 + cB*64 + lane];
            sv0 += eA.x*s0[cA] + eB.x*s0[cB];
            sv1 += eA.y*s0[N_NODES+cA] + eB.y*s0[N_NODES+cB];
        }
        if (j < end) {
            int cA = ecol[j]; float2 eA = ev2[2*j+1];
            a0 += eA.x * H1[cA*64 + lane];
            p0 += eA.y * H1[NN64 + cA*64 + lane];
            sv0 += eA.x*s0[cA]; sv1 += eA.y*s0[N_NODES+cA];
        }
        H2[r*64 + lane] = a0 + a1;
        H2[NN64 + r*64 + lane] = p0 + p1;
        if (lane == 0) { s1[r] = sv0; s1[N_NODES + r] = sv1; }
    }
    gbar(&bar[4]);

    // ---------------- P5: blend + dinv + M1d = dinv*(Hc @ w1) ----------------
    {
        int n = W;
        float x0 = Xp[n*64+lane], x1 = Xp[NN64 + n*64+lane];
        float h0 = H2[n*64+lane], h1v = H2[NN64 + n*64+lane];
        float hc = 0.5f*(fmaxf(0.5f*(x0+h0), 0.f) + fmaxf(0.5f*(x1+h1v), 0.f));
        float dv = rsqrtf(1.0f + s1[n] + s1[N_NODES+n]);
        if (lane == 0) dinv[n] = dv;
        float* hcs = (float*)lh;
        int wib = tid >> 6;
        hcs[wib*64 + lane] = hc;
        __syncthreads();
        int jj = lane & 15, quarter = lane >> 4;
        float acc = 0.f;
        #pragma unroll
        for (int k = 0; k < 16; k++) {
            int d = quarter*16 + k;
            acc += hcs[wib*64 + d] * w1[d*16 + jj];
        }
        acc += __shfl_xor(acc, 16);
        acc += __shfl_xor(acc, 32);
        if (lane < 16) M1d[n*16 + lane] = dv * acc;
    }
    gbar(&bar[5]);

    // ---------------- P6: U_c = mats_l0_c @ M1d ----------------
    {
        int r = W;
        int d = lane & 15;
        bool ch = (lane >> 4) & 1;
        bool hi = lane >= 32;
        int begin = row_start[r], end = row_start[r+1];
        float acc = 0.f;
        int j = begin;
        for (; j+2 <= end; j += 2) {
            int cA = ecol[j], cB = ecol[j+1];
            float2 eA = ev2[2*j], eB = ev2[2*j+2];
            float t0 = ch ? eA.y : eA.x;
            float t1 = ch ? eB.y : eB.x;
            float v  = hi ? t1 : t0;
            int col  = hi ? cB : cA;
            acc += v * M1d[col*16 + d];
        }
        if (j < end) {
            int cA = ecol[j]; float2 eA = ev2[2*j];
            float v = hi ? 0.f : (ch ? eA.y : eA.x);
            acc += v * M1d[cA*16 + d];
        }
        acc += __shfl_xor(acc, 32);
        if (lane < 32) U[(ch ? N_NODES*16 : 0) + r*16 + d] = acc;
    }
    gbar(&bar[6]);

    // ---------------- P7: P = mats_l1 @ U, h1 = relu(dinv*(P+M1d)+b1), M2d = dinv*(h1@w2) ----------------
    {
        int r = W;
        int d = lane & 15;
        bool ch = (lane >> 4) & 1;
        bool hi = lane >= 32;
        int chOff = ch ? N_NODES*16 : 0;
        int begin = row_start[r], end = row_start[r+1];
        float acc = 0.f;
        int j = begin;
        for (; j+2 <= end; j += 2) {
            int cA = ecol[j], cB = ecol[j+1];
            float2 eA = ev2[2*j+1], eB = ev2[2*j+3];
            float t0 = ch ? eA.y : eA.x;
            float t1 = ch ? eB.y : eB.x;
            float v  = hi ? t1 : t0;
            int col  = hi ? cB : cA;
            acc += v * U[chOff + col*16 + d];
        }
        if (j < end) {
            int cA = ecol[j]; float2 eA = ev2[2*j+1];
            float v = hi ? 0.f : (ch ? eA.y : eA.x);
            acc += v * U[chOff + cA*16 + d];
        }
        acc += __shfl_xor(acc, 32);
        acc += __shfl_xor(acc, 16);
        float dv = dinv[r];
        float hv = fmaxf(dv*(acc + M1d[r*16 + d]) + b1[d], 0.f);
        float m2 = 0.f;
        #pragma unroll
        for (int k = 0; k < 16; k++) m2 += __shfl(hv, k) * w2[k*64 + lane];
        M2d[r*64 + lane] = dv * m2;
    }
    gbar(&bar[7]);

    // ---------------- P8: V_c = mats_l0_c @ M2d (both channels) ----------------
    {
        int r = W;
        int begin = row_start[r], end = row_start[r+1];
        float a00=0.f,a01=0.f,a10=0.f,a11=0.f;
        int j = begin;
        for (; j+2 <= end; j += 2) {
            int cA = ecol[j], cB = ecol[j+1];
            float2 eA = ev2[2*j], eB = ev2[2*j+2];
            float xA = M2d[cA*64 + lane], xB = M2d[cB*64 + lane];
            a00 += eA.x*xA; a01 += eA.y*xA;
            a10 += eB.x*xB; a11 += eB.y*xB;
        }
        if (j < end) {
            int cA = ecol[j]; float2 eA = ev2[2*j];
            float xA = M2d[cA*64 + lane];
            a00 += eA.x*xA; a01 += eA.y*xA;
        }
        V[(size_t)r*64 + lane] = a00 + a10;
        V[(size_t)NN64 + r*64 + lane] = a01 + a11;
    }
    gbar(&bar[8]);

    // ---------------- P9: R = mats_l1 @ V (summed over ch) + log_softmax ----------------
    {
        int r = W;
        int begin = row_start[r], end = row_start[r+1];
        float a0=0.f, a1=0.f;
        int j = begin;
        for (; j+2 <= end; j += 2) {
            int cA = ecol[j], cB = ecol[j+1];
            float2 eA = ev2[2*j+1], eB = ev2[2*j+3];
            a0 += eA.x*V[cA*64+lane] + eA.y*V[NN64 + cA*64+lane];
            a1 += eB.x*V[cB*64+lane] + eB.y*V[NN64 + cB*64+lane];
        }
        if (j < end) {
            int cA = ecol[j]; float2 eA = ev2[2*j+1];
            a0 += eA.x*V[cA*64+lane] + eA.y*V[NN64 + cA*64+lane];
        }
        float v = dinv[r]*(a0 + a1 + M2d[r*64 + lane]) + b2[lane];
        float mx = v;
        #pragma unroll
        for (int o = 1; o < 64; o <<= 1) mx = fmaxf(mx, __shfl_xor(mx, o));
        float s = expf(v - mx);
        #pragma unroll
        for (int o = 1; o < 64; o <<= 1) s += __shfl_xor(s, o);
        hout[r*64 + lane] = v - mx - logf(s);
    }
    gbar(&bar[9]);

    // ---------------- P10: classification head ----------------
    {
        int g = b*NTHR + tid;
        if (g < NTGT*16) {
            int k = g & 15, i = g >> 4;
            int node = tgt[i];
            float acc = 0.f;
            #pragma unroll 8
            for (int d = 0; d < 64; d++) acc += hout[node*64 + d] * lin_w[d*16 + k];
            out[g] = acc + lin_b[k];
        }
    }
}

extern "C" void kernel_launch(void* const* d_in, const int* in_sizes, int n_in,
                              void* d_out, int out_size, void* d_ws, size_t ws_size,
                              hipStream_t stream) {
    const float* X          = (const float*)d_in[0];
    const float* edge_value = (const float*)d_in[1];
    const float* conv_w     = (const float*)d_in[2];
    const float* Ws         = (const float*)d_in[3];
    const float* w1         = (const float*)d_in[4];
    const float* b1         = (const float*)d_in[5];
    const float* w2         = (const float*)d_in[6];
    const float* b2         = (const float*)d_in[7];
    const float* lin_w      = (const float*)d_in[8];
    const float* lin_b      = (const float*)d_in[9];
    const int*   ei         = (const int*)d_in[10];
    const int*   tgt        = (const int*)d_in[11];
    float* ws = (float*)d_ws;

    hipMemsetAsync(ws + OFF_BAR, 0, 16*sizeof(int), stream);
    k_mega<<<GB, NTHR, 0, stream>>>(X, edge_value, conv_w, Ws, w1, b1, w2, b2,
                                    lin_w, lin_b, ei, tgt, (float*)d_out, ws);
}

// Round 4
// 230.201 us; speedup vs baseline: 5.6798x; 5.6798x over previous
//
#include <hip/hip_runtime.h>
#include <math.h>

#define N_NODES 2048
#define NN64 (N_NODES*64)
#define NET 3
#define NE 65536
#define TE 196608
#define W_IN 256
#define NTGT 512

// workspace float offsets
#define OFF_FILT  0
#define OFF_CNT   16
#define OFF_CUR   2064
#define OFF_RS    4112
#define OFF_ECOL  6176
#define OFF_EV    202784
#define OFF_XP    989216
#define OFF_H1    1251360
#define OFF_S0    1513504
#define OFF_DINV  1517600
#define OFF_M1D   1519648
#define OFF_U     1552416
#define OFF_M2D   1617952
#define OFF_V     1749024
#define OFF_HOUT  2011168

// ---------------- init: filt + direct histogram + projection (both channels) ----------------
__global__ __launch_bounds__(256) void k_init(
    const float* __restrict__ conv_w, const float* __restrict__ X,
    const float* __restrict__ Ws, const int* __restrict__ ei,
    float* __restrict__ filt, int* __restrict__ counts, float2* __restrict__ Xp2) {
    int b = blockIdx.x, tid = threadIdx.x;
    if (b < 64) {
        if (b == 0 && tid < 4) {
            float a = conv_w[tid*3+0], bb = conv_w[tid*3+1], cc = conv_w[tid*3+2];
            float m = fmaxf(a, fmaxf(bb, cc));
            float ea = expf(a-m), eb = expf(bb-m), ec = expf(cc-m);
            float s = ea + eb + ec;
            filt[tid*3+0] = ea/s; filt[tid*3+1] = eb/s; filt[tid*3+2] = ec/s;
        }
        for (int e = b*3072 + tid; e < (b+1)*3072; e += 256) {
            int t = e >> 16, idx = e & 0xFFFF;
            atomicAdd(&counts[ei[t*2*NE + idx]], 1);
        }
    } else {
        int g = (b-64)*256 + tid;      // 0..32767
        int d = g & 63;
        int grp = g >> 6;              // 0..511 (4 nodes each)
        const float* w0 = Ws + d;
        const float* w1p = Ws + W_IN*64 + d;
        const float* x0 = X + (grp*4)*W_IN;
        float a00=0.f,a01=0.f,a10=0.f,a11=0.f,a20=0.f,a21=0.f,a30=0.f,a31=0.f;
        for (int f = 0; f < W_IN; ++f) {
            float wa = w0[f*64], wb = w1p[f*64];
            float xa = x0[f], xb_ = x0[W_IN+f], xc = x0[2*W_IN+f], xd = x0[3*W_IN+f];
            a00 += xa*wa;  a01 += xa*wb;
            a10 += xb_*wa; a11 += xb_*wb;
            a20 += xc*wa;  a21 += xc*wb;
            a30 += xd*wa;  a31 += xd*wb;
        }
        Xp2[(grp*4+0)*64 + d] = make_float2(a00, a01);
        Xp2[(grp*4+1)*64 + d] = make_float2(a10, a11);
        Xp2[(grp*4+2)*64 + d] = make_float2(a20, a21);
        Xp2[(grp*4+3)*64 + d] = make_float2(a30, a31);
    }
}

// ---------------- build: redundant per-block scan + CSR scatter with pre-scaled values ----------------
__global__ __launch_bounds__(256) void k_build(
    const int* __restrict__ counts, const int* __restrict__ ei,
    const float* __restrict__ edge_value, const float* __restrict__ filt,
    int* __restrict__ cursor, int* __restrict__ row_start,
    int* __restrict__ ecol, float4* __restrict__ ev4) {
    __shared__ int rs_l[N_NODES+1];
    __shared__ int pref[256];
    int tid = threadIdx.x, b = blockIdx.x;
    int loc[8]; int s = 0;
    #pragma unroll
    for (int k = 0; k < 8; k++) { loc[k] = s; s += counts[tid*8 + k]; }
    pref[tid] = s;
    __syncthreads();
    for (int off = 1; off < 256; off <<= 1) {
        int v = (tid >= off) ? pref[tid - off] : 0;
        __syncthreads();
        pref[tid] += v;
        __syncthreads();
    }
    int base = tid ? pref[tid-1] : 0;
    #pragma unroll
    for (int k = 0; k < 8; k++) rs_l[tid*8 + k] = base + loc[k];
    if (tid == 255) rs_l[N_NODES] = pref[255];
    __syncthreads();
    if (b == 0) for (int k = tid; k <= N_NODES; k += 256) row_start[k] = rs_l[k];

    float fl[12];
    #pragma unroll
    for (int k = 0; k < 12; k++) fl[k] = filt[k];
    const int per = TE/128;   // 1536
    for (int e = b*per + tid; e < (b+1)*per; e += 256) {
        int t = e >> 16, idx = e & 0xFFFF;
        int row = ei[t*2*NE + idx];
        int col = ei[t*2*NE + NE + idx];
        float ev = edge_value[e];
        int pos = rs_l[row] + atomicAdd(&cursor[row], 1);
        float f00 = (t==0)?fl[0]:((t==1)?fl[1]:fl[2]);
        float f01 = (t==0)?fl[3]:((t==1)?fl[4]:fl[5]);
        float f10 = (t==0)?fl[6]:((t==1)?fl[7]:fl[8]);
        float f11 = (t==0)?fl[9]:((t==1)?fl[10]:fl[11]);
        ecol[pos] = col;
        ev4[pos] = make_float4(ev*f00, ev*f01, ev*f10, ev*f11);
    }
}

// ---------------- H pass 1: H1 = mats_l0 @ Xp (both ch), s0 = rowsum; block per row ----------------
__global__ __launch_bounds__(256) void k_h0(
    const int* __restrict__ rs, const int* __restrict__ ecol,
    const float2* __restrict__ ev2, const float2* __restrict__ Xp2,
    float2* __restrict__ H12, float2* __restrict__ s02) {
    __shared__ float redA[4][64], redP[4][64], rv[4][2];
    int r = blockIdx.x;
    int wv = threadIdx.x >> 6, lane = threadIdx.x & 63;
    int begin = rs[r], end = rs[r+1], len = end - begin;
    int q0 = begin + ((len*wv) >> 2), q1 = begin + ((len*(wv+1)) >> 2);
    float a0=0.f,a1=0.f,p0=0.f,p1=0.f, vs0=0.f, vs1=0.f;

    auto PROC = [&](int c0,int c1,int c2,int c3,float2 e0,float2 e1,float2 e2,float2 e3){
        float2 x0=Xp2[c0*64+lane], x1=Xp2[c1*64+lane], x2=Xp2[c2*64+lane], x3=Xp2[c3*64+lane];
        a0 += e0.x*x0.x; p0 += e0.y*x0.y;
        a1 += e1.x*x1.x; p1 += e1.y*x1.y;
        a0 += e2.x*x2.x; p0 += e2.y*x2.y;
        a1 += e3.x*x3.x; p1 += e3.y*x3.y;
        vs0 += (e0.x+e1.x)+(e2.x+e3.x);
        vs1 += (e0.y+e1.y)+(e2.y+e3.y);
    };
    int j = q0, n4 = (q1-q0) & ~3, j4 = q0 + n4;
    if (n4) {
        int c0=ecol[j],c1=ecol[j+1],c2=ecol[j+2],c3=ecol[j+3];
        float2 e0=ev2[2*j],e1=ev2[2*(j+1)],e2=ev2[2*(j+2)],e3=ev2[2*(j+3)];
        for (j += 4; j < j4; j += 4) {
            int d0=ecol[j],d1=ecol[j+1],d2=ecol[j+2],d3=ecol[j+3];
            float2 f0=ev2[2*j],f1=ev2[2*(j+1)],f2=ev2[2*(j+2)],f3=ev2[2*(j+3)];
            PROC(c0,c1,c2,c3,e0,e1,e2,e3);
            c0=d0;c1=d1;c2=d2;c3=d3; e0=f0;e1=f1;e2=f2;e3=f3;
        }
        PROC(c0,c1,c2,c3,e0,e1,e2,e3);
    }
    for (; j < q1; ++j) {
        int c = ecol[j]; float2 e = ev2[2*j]; float2 x = Xp2[c*64+lane];
        a0 += e.x*x.x; p0 += e.y*x.y; vs0 += e.x; vs1 += e.y;
    }
    redA[wv][lane] = a0+a1; redP[wv][lane] = p0+p1;
    if (lane == 0) { rv[wv][0] = vs0; rv[wv][1] = vs1; }
    __syncthreads();
    if (wv == 0) {
        float A = redA[0][lane]+redA[1][lane]+redA[2][lane]+redA[3][lane];
        float P = redP[0][lane]+redP[1][lane]+redP[2][lane]+redP[3][lane];
        H12[r*64 + lane] = make_float2(A, P);
        if (lane == 0)
            s02[r] = make_float2(rv[0][0]+rv[1][0]+rv[2][0]+rv[3][0],
                                 rv[0][1]+rv[1][1]+rv[2][1]+rv[3][1]);
    }
}

// ---------------- H pass 2 fused: H2 + s1 + blend + dinv + M1d ----------------
__global__ __launch_bounds__(256) void k_h1(
    const int* __restrict__ rs, const int* __restrict__ ecol,
    const float2* __restrict__ ev2, const float2* __restrict__ H12,
    const float2* __restrict__ s02, const float2* __restrict__ Xp2,
    const float* __restrict__ w1, float* __restrict__ dinv, float* __restrict__ M1d) {
    __shared__ float redA[4][64], redP[4][64], rv[4][2];
    int r = blockIdx.x;
    int wv = threadIdx.x >> 6, lane = threadIdx.x & 63;
    int begin = rs[r], end = rs[r+1], len = end - begin;
    int q0 = begin + ((len*wv) >> 2), q1 = begin + ((len*(wv+1)) >> 2);
    float a0=0.f,a1=0.f,p0=0.f,p1=0.f, sv0=0.f, sv1=0.f;

    auto PROC = [&](int c0,int c1,int c2,int c3,float2 e0,float2 e1,float2 e2,float2 e3){
        float2 x0=H12[c0*64+lane], x1=H12[c1*64+lane], x2=H12[c2*64+lane], x3=H12[c3*64+lane];
        float2 s0v=s02[c0], s1v=s02[c1], s2v=s02[c2], s3v=s02[c3];
        a0 += e0.x*x0.x; p0 += e0.y*x0.y;
        a1 += e1.x*x1.x; p1 += e1.y*x1.y;
        a0 += e2.x*x2.x; p0 += e2.y*x2.y;
        a1 += e3.x*x3.x; p1 += e3.y*x3.y;
        sv0 += (e0.x*s0v.x + e1.x*s1v.x) + (e2.x*s2v.x + e3.x*s3v.x);
        sv1 += (e0.y*s0v.y + e1.y*s1v.y) + (e2.y*s2v.y + e3.y*s3v.y);
    };
    int j = q0, n4 = (q1-q0) & ~3, j4 = q0 + n4;
    if (n4) {
        int c0=ecol[j],c1=ecol[j+1],c2=ecol[j+2],c3=ecol[j+3];
        float2 e0=ev2[2*j+1],e1=ev2[2*(j+1)+1],e2=ev2[2*(j+2)+1],e3=ev2[2*(j+3)+1];
        for (j += 4; j < j4; j += 4) {
            int d0=ecol[j],d1=ecol[j+1],d2=ecol[j+2],d3=ecol[j+3];
            float2 f0=ev2[2*j+1],f1=ev2[2*(j+1)+1],f2=ev2[2*(j+2)+1],f3=ev2[2*(j+3)+1];
            PROC(c0,c1,c2,c3,e0,e1,e2,e3);
            c0=d0;c1=d1;c2=d2;c3=d3; e0=f0;e1=f1;e2=f2;e3=f3;
        }
        PROC(c0,c1,c2,c3,e0,e1,e2,e3);
    }
    for (; j < q1; ++j) {
        int c = ecol[j]; float2 e = ev2[2*j+1]; float2 x = H12[c*64+lane]; float2 sv = s02[c];
        a0 += e.x*x.x; p0 += e.y*x.y; sv0 += e.x*sv.x; sv1 += e.y*sv.y;
    }
    redA[wv][lane] = a0+a1; redP[wv][lane] = p0+p1;
    if (lane == 0) { rv[wv][0] = sv0; rv[wv][1] = sv1; }
    __syncthreads();
    if (wv == 0) {
        float A = redA[0][lane]+redA[1][lane]+redA[2][lane]+redA[3][lane];
        float P = redP[0][lane]+redP[1][lane]+redP[2][lane]+redP[3][lane];
        float SV0 = rv[0][0]+rv[1][0]+rv[2][0]+rv[3][0];
        float SV1 = rv[0][1]+rv[1][1]+rv[2][1]+rv[3][1];
        float dv = rsqrtf(1.0f + SV0 + SV1);
        float2 x = Xp2[r*64 + lane];
        float hc = 0.5f*(fmaxf(0.5f*(x.x + A), 0.f) + fmaxf(0.5f*(x.y + P), 0.f));
        if (lane == 0) dinv[r] = dv;
        int jj = lane & 15, quarter = lane >> 4;
        float acc = 0.f;
        #pragma unroll
        for (int k = 0; k < 16; k++) {
            int d = quarter*16 + k;
            acc += __shfl(hc, d) * w1[d*16 + jj];
        }
        acc += __shfl_xor(acc, 16);
        acc += __shfl_xor(acc, 32);
        if (lane < 16) M1d[r*16 + lane] = dv * acc;
    }
}

// ---------------- GCN16 pass 1: U = mats_l0 @ M1d ----------------
__global__ __launch_bounds__(256) void k_g1a(
    const int* __restrict__ rs, const int* __restrict__ ecol,
    const float2* __restrict__ ev2, const float* __restrict__ M1d,
    float* __restrict__ U2) {
    __shared__ float red[4][32];
    int r = blockIdx.x;
    int wv = threadIdx.x >> 6, lane = threadIdx.x & 63;
    int d = lane & 15, ch = (lane >> 4) & 1, ep = lane >> 5;
    int begin = rs[r], end = rs[r+1], len = end - begin;
    int q0 = begin + ((len*wv) >> 2), q1 = begin + ((len*(wv+1)) >> 2);
    float acc = 0.f;
    int j = q0, n4 = (q1-q0) & ~3, j4 = q0 + n4;
    if (n4) {
        int cA = ecol[j+ep], cB = ecol[j+2+ep];
        float2 EA = ev2[2*(j+ep)], EB = ev2[2*(j+2+ep)];
        for (j += 4; j < j4; j += 4) {
            int nA = ecol[j+ep], nB = ecol[j+2+ep];
            float2 FA = ev2[2*(j+ep)], FB = ev2[2*(j+2+ep)];
            acc += (ch ? EA.y : EA.x) * M1d[cA*16 + d];
            acc += (ch ? EB.y : EB.x) * M1d[cB*16 + d];
            cA = nA; cB = nB; EA = FA; EB = FB;
        }
        acc += (ch ? EA.y : EA.x) * M1d[cA*16 + d];
        acc += (ch ? EB.y : EB.x) * M1d[cB*16 + d];
    }
    for (; j < q1; ++j) {
        int c = ecol[j]; float2 e = ev2[2*j];
        if (ep == 0) acc += (ch ? e.y : e.x) * M1d[c*16 + d];
    }
    acc += __shfl_xor(acc, 32);
    if (lane < 32) red[wv][lane] = acc;
    __syncthreads();
    if (wv == 0 && lane < 32) {
        float s = red[0][lane]+red[1][lane]+red[2][lane]+red[3][lane];
        U2[r*32 + d*2 + ch] = s;
    }
}

// ---------------- GCN16 pass 2 fused: P + h1 + M2d ----------------
__global__ __launch_bounds__(256) void k_g1b(
    const int* __restrict__ rs, const int* __restrict__ ecol,
    const float2* __restrict__ ev2, const float* __restrict__ U2,
    const float* __restrict__ M1d, const float* __restrict__ dinv,
    const float* __restrict__ b1, const float* __restrict__ w2,
    float* __restrict__ M2d) {
    __shared__ float red[4][32];
    int r = blockIdx.x;
    int wv = threadIdx.x >> 6, lane = threadIdx.x & 63;
    int d = lane & 15, ch = (lane >> 4) & 1, ep = lane >> 5;
    int begin = rs[r], end = rs[r+1], len = end - begin;
    int q0 = begin + ((len*wv) >> 2), q1 = begin + ((len*(wv+1)) >> 2);
    float acc = 0.f;
    int j = q0, n4 = (q1-q0) & ~3, j4 = q0 + n4;
    if (n4) {
        int cA = ecol[j+ep], cB = ecol[j+2+ep];
        float2 EA = ev2[2*(j+ep)+1], EB = ev2[2*(j+2+ep)+1];
        for (j += 4; j < j4; j += 4) {
            int nA = ecol[j+ep], nB = ecol[j+2+ep];
            float2 FA = ev2[2*(j+ep)+1], FB = ev2[2*(j+2+ep)+1];
            acc += (ch ? EA.y : EA.x) * U2[cA*32 + d*2 + ch];
            acc += (ch ? EB.y : EB.x) * U2[cB*32 + d*2 + ch];
            cA = nA; cB = nB; EA = FA; EB = FB;
        }
        acc += (ch ? EA.y : EA.x) * U2[cA*32 + d*2 + ch];
        acc += (ch ? EB.y : EB.x) * U2[cB*32 + d*2 + ch];
    }
    for (; j < q1; ++j) {
        int c = ecol[j]; float2 e = ev2[2*j+1];
        if (ep == 0) acc += (ch ? e.y : e.x) * U2[c*32 + d*2 + ch];
    }
    acc += __shfl_xor(acc, 32);
    if (lane < 32) red[wv][lane] = acc;
    __syncthreads();
    if (wv == 0) {
        float Pv = red[0][lane&31]+red[1][lane&31]+red[2][lane&31]+red[3][lane&31];
        Pv += __shfl_xor(Pv, 16);
        float dv = dinv[r];
        float hv = fmaxf(dv*(Pv + M1d[r*16 + (lane&15)]) + b1[lane&15], 0.f);
        float m2 = 0.f;
        #pragma unroll
        for (int k = 0; k < 16; k++) m2 += __shfl(hv, k) * w2[k*64 + lane];
        M2d[r*64 + lane] = dv * m2;
    }
}

// ---------------- GCN64 pass 1: V = mats_l0 @ M2d (both ch) ----------------
__global__ __launch_bounds__(256) void k_g2a(
    const int* __restrict__ rs, const int* __restrict__ ecol,
    const float2* __restrict__ ev2, const float* __restrict__ M2d,
    float2* __restrict__ V2) {
    __shared__ float redA[4][64], redP[4][64];
    int r = blockIdx.x;
    int wv = threadIdx.x >> 6, lane = threadIdx.x & 63;
    int begin = rs[r], end = rs[r+1], len = end - begin;
    int q0 = begin + ((len*wv) >> 2), q1 = begin + ((len*(wv+1)) >> 2);
    float a0=0.f,a1=0.f,p0=0.f,p1=0.f;
    auto PROC = [&](int c0,int c1,int c2,int c3,float2 e0,float2 e1,float2 e2,float2 e3){
        float x0=M2d[c0*64+lane], x1=M2d[c1*64+lane], x2=M2d[c2*64+lane], x3=M2d[c3*64+lane];
        a0 += e0.x*x0; p0 += e0.y*x0;
        a1 += e1.x*x1; p1 += e1.y*x1;
        a0 += e2.x*x2; p0 += e2.y*x2;
        a1 += e3.x*x3; p1 += e3.y*x3;
    };
    int j = q0, n4 = (q1-q0) & ~3, j4 = q0 + n4;
    if (n4) {
        int c0=ecol[j],c1=ecol[j+1],c2=ecol[j+2],c3=ecol[j+3];
        float2 e0=ev2[2*j],e1=ev2[2*(j+1)],e2=ev2[2*(j+2)],e3=ev2[2*(j+3)];
        for (j += 4; j < j4; j += 4) {
            int d0=ecol[j],d1=ecol[j+1],d2=ecol[j+2],d3=ecol[j+3];
            float2 f0=ev2[2*j],f1=ev2[2*(j+1)],f2=ev2[2*(j+2)],f3=ev2[2*(j+3)];
            PROC(c0,c1,c2,c3,e0,e1,e2,e3);
            c0=d0;c1=d1;c2=d2;c3=d3; e0=f0;e1=f1;e2=f2;e3=f3;
        }
        PROC(c0,c1,c2,c3,e0,e1,e2,e3);
    }
    for (; j < q1; ++j) {
        int c = ecol[j]; float2 e = ev2[2*j]; float x = M2d[c*64+lane];
        a0 += e.x*x; p0 += e.y*x;
    }
    redA[wv][lane] = a0+a1; redP[wv][lane] = p0+p1;
    __syncthreads();
    if (wv == 0) {
        float A = redA[0][lane]+redA[1][lane]+redA[2][lane]+redA[3][lane];
        float P = redP[0][lane]+redP[1][lane]+redP[2][lane]+redP[3][lane];
        V2[r*64 + lane] = make_float2(A, P);
    }
}

// ---------------- GCN64 pass 2 fused: R + log_softmax ----------------
__global__ __launch_bounds__(256) void k_g2b(
    const int* __restrict__ rs, const int* __restrict__ ecol,
    const float2* __restrict__ ev2, const float2* __restrict__ V2,
    const float* __restrict__ M2d, const float* __restrict__ dinv,
    const float* __restrict__ b2, float* __restrict__ hout) {
    __shared__ float red[4][64];
    int r = blockIdx.x;
    int wv = threadIdx.x >> 6, lane = threadIdx.x & 63;
    int begin = rs[r], end = rs[r+1], len = end - begin;
    int q0 = begin + ((len*wv) >> 2), q1 = begin + ((len*(wv+1)) >> 2);
    float a0=0.f, a1=0.f;
    auto PROC = [&](int c0,int c1,int c2,int c3,float2 e0,float2 e1,float2 e2,float2 e3){
        float2 x0=V2[c0*64+lane], x1=V2[c1*64+lane], x2=V2[c2*64+lane], x3=V2[c3*64+lane];
        a0 += e0.x*x0.x + e0.y*x0.y;
        a1 += e1.x*x1.x + e1.y*x1.y;
        a0 += e2.x*x2.x + e2.y*x2.y;
        a1 += e3.x*x3.x + e3.y*x3.y;
    };
    int j = q0, n4 = (q1-q0) & ~3, j4 = q0 + n4;
    if (n4) {
        int c0=ecol[j],c1=ecol[j+1],c2=ecol[j+2],c3=ecol[j+3];
        float2 e0=ev2[2*j+1],e1=ev2[2*(j+1)+1],e2=ev2[2*(j+2)+1],e3=ev2[2*(j+3)+1];
        for (j += 4; j < j4; j += 4) {
            int d0=ecol[j],d1=ecol[j+1],d2=ecol[j+2],d3=ecol[j+3];
            float2 f0=ev2[2*j+1],f1=ev2[2*(j+1)+1],f2=ev2[2*(j+2)+1],f3=ev2[2*(j+3)+1];
            PROC(c0,c1,c2,c3,e0,e1,e2,e3);
            c0=d0;c1=d1;c2=d2;c3=d3; e0=f0;e1=f1;e2=f2;e3=f3;
        }
        PROC(c0,c1,c2,c3,e0,e1,e2,e3);
    }
    for (; j < q1; ++j) {
        int c = ecol[j]; float2 e = ev2[2*j+1]; float2 x = V2[c*64+lane];
        a0 += e.x*x.x + e.y*x.y;
    }
    red[wv][lane] = a0+a1;
    __syncthreads();
    if (wv == 0) {
        float S = red[0][lane]+red[1][lane]+red[2][lane]+red[3][lane];
        float v = dinv[r]*(S + M2d[r*64 + lane]) + b2[lane];
        float mx = v;
        #pragma unroll
        for (int o = 1; o < 64; o <<= 1) mx = fmaxf(mx, __shfl_xor(mx, o));
        float s = expf(v - mx);
        #pragma unroll
        for (int o = 1; o < 64; o <<= 1) s += __shfl_xor(s, o);
        hout[r*64 + lane] = v - mx - logf(s);
    }
}

// ---------------- head ----------------
__global__ __launch_bounds__(256) void k_out(
    const float* __restrict__ hout, const int* __restrict__ tgt,
    const float* __restrict__ lin_w, const float* __restrict__ lin_b,
    float* __restrict__ y) {
    int g = blockIdx.x*256 + threadIdx.x;   // NTGT*16
    int k = g & 15, i = g >> 4;
    int node = tgt[i];
    float acc = 0.f;
    #pragma unroll 8
    for (int d = 0; d < 64; d++) acc += hout[node*64 + d] * lin_w[d*16 + k];
    y[g] = acc + lin_b[k];
}

// ---------------- launch ----------------
extern "C" void kernel_launch(void* const* d_in, const int* in_sizes, int n_in,
                              void* d_out, int out_size, void* d_ws, size_t ws_size,
                              hipStream_t stream) {
    const float* X          = (const float*)d_in[0];
    const float* edge_value = (const float*)d_in[1];
    const float* conv_w     = (const float*)d_in[2];
    const float* Ws         = (const float*)d_in[3];
    const float* w1         = (const float*)d_in[4];
    const float* b1         = (const float*)d_in[5];
    const float* w2         = (const float*)d_in[6];
    const float* b2         = (const float*)d_in[7];
    const float* lin_w      = (const float*)d_in[8];
    const float* lin_b      = (const float*)d_in[9];
    const int*   ei         = (const int*)d_in[10];
    const int*   tgt        = (const int*)d_in[11];
    float* out = (float*)d_out;

    float* ws = (float*)d_ws;
    float*  filt      = ws + OFF_FILT;
    int*    counts    = (int*)(ws + OFF_CNT);
    int*    cursor    = (int*)(ws + OFF_CUR);
    int*    row_start = (int*)(ws + OFF_RS);
    int*    ecol      = (int*)(ws + OFF_ECOL);
    float4* ev4       = (float4*)(ws + OFF_EV);
    const float2* ev2 = (const float2*)(ws + OFF_EV);
    float2* Xp2  = (float2*)(ws + OFF_XP);
    float2* H12  = (float2*)(ws + OFF_H1);
    float2* s02  = (float2*)(ws + OFF_S0);
    float*  dinv = ws + OFF_DINV;
    float*  M1d  = ws + OFF_M1D;
    float*  U2   = ws + OFF_U;
    float*  M2d  = ws + OFF_M2D;
    float2* V2   = (float2*)(ws + OFF_V);
    float*  hout = ws + OFF_HOUT;

    hipMemsetAsync(ws + OFF_CNT, 0, 4096*sizeof(int), stream);   // counts + cursor
    k_init <<<192, 256, 0, stream>>>(conv_w, X, Ws, ei, filt, counts, Xp2);
    k_build<<<128, 256, 0, stream>>>(counts, ei, edge_value, filt, cursor, row_start, ecol, ev4);
    k_h0  <<<N_NODES, 256, 0, stream>>>(row_start, ecol, ev2, Xp2, H12, s02);
    k_h1  <<<N_NODES, 256, 0, stream>>>(row_start, ecol, ev2, H12, s02, Xp2, w1, dinv, M1d);
    k_g1a <<<N_NODES, 256, 0, stream>>>(row_start, ecol, ev2, M1d, U2);
    k_g1b <<<N_NODES, 256, 0, stream>>>(row_start, ecol, ev2, U2, M1d, dinv, b1, w2, M2d);
    k_g2a <<<N_NODES, 256, 0, stream>>>(row_start, ecol, ev2, M2d, V2);
    k_g2b <<<N_NODES, 256, 0, stream>>>(row_start, ecol, ev2, V2, M2d, dinv, b2, hout);
    k_out <<<NTGT*16/256, 256, 0, stream>>>(hout, tgt, lin_w, lin_b, out);
}

// Round 5
// 204.837 us; speedup vs baseline: 6.3831x; 1.1238x over previous
//
#include <hip/hip_runtime.h>
#include <math.h>

#define N_NODES 2048
#define NET 3
#define NE 65536
#define TE 196608
#define W_IN 256
#define NTGT 512
#define CAP 192

// workspace float offsets
#define OFF_CNT   0
#define OFF_ECOL  2048
#define OFF_EV    395264
#define OFF_XP    1968128
#define OFF_H1    2230272
#define OFF_S0    2492416
#define OFF_DINV  2496512
#define OFF_M1D   2498560
#define OFF_U     2531328
#define OFF_M2D   2596864
#define OFF_V     2727936

// ---------------- init: bucket-scatter (blocks 0..63) + projection (blocks 64..191) ----------------
__global__ __launch_bounds__(256) void k_init(
    const float* __restrict__ conv_w, const float* __restrict__ X,
    const float* __restrict__ Ws, const int* __restrict__ ei,
    const float* __restrict__ edge_value,
    int* __restrict__ cnt, int* __restrict__ ecol, float4* __restrict__ ev4,
    float2* __restrict__ Xp2) {
    int b = blockIdx.x, tid = threadIdx.x;
    if (b < 64) {
        // per-thread softmax filters: fl[l*2+c][t]
        float f00[3], f01[3], f10[3], f11[3];
        {
            #pragma unroll
            for (int i = 0; i < 4; i++) {
                float a = conv_w[i*3+0], bb = conv_w[i*3+1], cc = conv_w[i*3+2];
                float m = fmaxf(a, fmaxf(bb, cc));
                float ea = expf(a-m), eb = expf(bb-m), ec = expf(cc-m);
                float s = 1.0f/(ea + eb + ec);
                float* dst = (i==0)?f00:((i==1)?f01:((i==2)?f10:f11));
                dst[0] = ea*s; dst[1] = eb*s; dst[2] = ec*s;
            }
        }
        for (int e = b*3072 + tid; e < (b+1)*3072; e += 256) {
            int t = e >> 16, idx = e & 0xFFFF;
            int row = ei[t*2*NE + idx];
            int col = ei[t*2*NE + NE + idx];
            float ev = edge_value[e];
            int pos = atomicAdd(&cnt[row], 1);
            if (pos < CAP) {
                ecol[row*CAP + pos] = col;
                ev4[row*CAP + pos] = make_float4(ev*f00[t], ev*f01[t], ev*f10[t], ev*f11[t]);
            }
        }
    } else {
        int g = (b-64)*256 + tid;      // 0..32767
        int d = g & 63;
        int grp = g >> 6;              // 0..511 (4 nodes each)
        const float* w0  = Ws + d;
        const float* w1p = Ws + W_IN*64 + d;
        const float* x0  = X + (grp*4)*W_IN;
        float a00=0.f,a01=0.f,a10=0.f,a11=0.f,a20=0.f,a21=0.f,a30=0.f,a31=0.f;
        for (int f = 0; f < W_IN; ++f) {
            float wa = w0[f*64], wb = w1p[f*64];
            float xa = x0[f], xb_ = x0[W_IN+f], xc = x0[2*W_IN+f], xd = x0[3*W_IN+f];
            a00 += xa*wa;  a01 += xa*wb;
            a10 += xb_*wa; a11 += xb_*wb;
            a20 += xc*wa;  a21 += xc*wb;
            a30 += xd*wa;  a31 += xd*wb;
        }
        Xp2[(grp*4+0)*64 + d] = make_float2(a00, a01);
        Xp2[(grp*4+1)*64 + d] = make_float2(a10, a11);
        Xp2[(grp*4+2)*64 + d] = make_float2(a20, a21);
        Xp2[(grp*4+3)*64 + d] = make_float2(a30, a31);
    }
}

// ---------------- H pass 1: H1 = M0 @ Xp (both ch), s0 = rowsums of M0 ----------------
__global__ __launch_bounds__(256) void k_h0(
    const int* __restrict__ cnt, const int* __restrict__ ecol,
    const float4* __restrict__ ev4, const float2* __restrict__ Xp2,
    float2* __restrict__ H12, float2* __restrict__ s02) {
    __shared__ float redA[4][64], redP[4][64], rv[4][2];
    int r = blockIdx.x;
    int wv = threadIdx.x >> 6, lane = threadIdx.x & 63;
    int len = min(cnt[r], CAP), base = r*CAP;
    int q0 = (len*wv) >> 2, q1 = (len*(wv+1)) >> 2;
    float a0=0.f,a1=0.f,p0=0.f,p1=0.f, vs0=0.f, vs1=0.f;
    int j = q0;
    for (; j+2 <= q1; j += 2) {
        int cA = ecol[base+j], cB = ecol[base+j+1];
        float4 eA = ev4[base+j], eB = ev4[base+j+1];
        float2 xA = Xp2[cA*64+lane], xB = Xp2[cB*64+lane];
        a0 += eA.x*xA.x; p0 += eA.y*xA.y;
        a1 += eB.x*xB.x; p1 += eB.y*xB.y;
        vs0 += eA.x + eB.x; vs1 += eA.y + eB.y;
    }
    if (j < q1) {
        int cA = ecol[base+j]; float4 eA = ev4[base+j];
        float2 xA = Xp2[cA*64+lane];
        a0 += eA.x*xA.x; p0 += eA.y*xA.y;
        vs0 += eA.x; vs1 += eA.y;
    }
    redA[wv][lane] = a0+a1; redP[wv][lane] = p0+p1;
    if (lane == 0) { rv[wv][0] = vs0; rv[wv][1] = vs1; }
    __syncthreads();
    if (wv == 0) {
        float A = redA[0][lane]+redA[1][lane]+redA[2][lane]+redA[3][lane];
        float P = redP[0][lane]+redP[1][lane]+redP[2][lane]+redP[3][lane];
        H12[r*64 + lane] = make_float2(A, P);
        if (lane == 0)
            s02[r] = make_float2(rv[0][0]+rv[1][0]+rv[2][0]+rv[3][0],
                                 rv[0][1]+rv[1][1]+rv[2][1]+rv[3][1]);
    }
}

// ---------------- H pass 2 fused: H2 = M1 @ H1, s1 = M1 @ s0, blend + dinv + M1d ----------------
__global__ __launch_bounds__(256) void k_h1(
    const int* __restrict__ cnt, const int* __restrict__ ecol,
    const float4* __restrict__ ev4, const float2* __restrict__ H12,
    const float2* __restrict__ s02, const float2* __restrict__ Xp2,
    const float* __restrict__ w1, float* __restrict__ dinv, float* __restrict__ M1d) {
    __shared__ float redA[4][64], redP[4][64], rv[4][2];
    int r = blockIdx.x;
    int wv = threadIdx.x >> 6, lane = threadIdx.x & 63;
    int len = min(cnt[r], CAP), base = r*CAP;
    int q0 = (len*wv) >> 2, q1 = (len*(wv+1)) >> 2;
    float a0=0.f,a1=0.f,p0=0.f,p1=0.f, sv0=0.f, sv1=0.f;
    int j = q0;
    for (; j+2 <= q1; j += 2) {
        int cA = ecol[base+j], cB = ecol[base+j+1];
        float4 eA = ev4[base+j], eB = ev4[base+j+1];
        float2 xA = H12[cA*64+lane], xB = H12[cB*64+lane];
        float2 sA = s02[cA], sB = s02[cB];
        a0 += eA.z*xA.x; p0 += eA.w*xA.y;
        a1 += eB.z*xB.x; p1 += eB.w*xB.y;
        sv0 += eA.z*sA.x + eB.z*sB.x;
        sv1 += eA.w*sA.y + eB.w*sB.y;
    }
    if (j < q1) {
        int cA = ecol[base+j]; float4 eA = ev4[base+j];
        float2 xA = H12[cA*64+lane]; float2 sA = s02[cA];
        a0 += eA.z*xA.x; p0 += eA.w*xA.y;
        sv0 += eA.z*sA.x; sv1 += eA.w*sA.y;
    }
    redA[wv][lane] = a0+a1; redP[wv][lane] = p0+p1;
    if (lane == 0) { rv[wv][0] = sv0; rv[wv][1] = sv1; }
    __syncthreads();
    if (wv == 0) {
        float A = redA[0][lane]+redA[1][lane]+redA[2][lane]+redA[3][lane];
        float P = redP[0][lane]+redP[1][lane]+redP[2][lane]+redP[3][lane];
        float SV0 = rv[0][0]+rv[1][0]+rv[2][0]+rv[3][0];
        float SV1 = rv[0][1]+rv[1][1]+rv[2][1]+rv[3][1];
        float dv = rsqrtf(1.0f + SV0 + SV1);
        float2 x = Xp2[r*64 + lane];
        float hc = 0.5f*(fmaxf(0.5f*(x.x + A), 0.f) + fmaxf(0.5f*(x.y + P), 0.f));
        if (lane == 0) dinv[r] = dv;
        int jj = lane & 15, quarter = lane >> 4;
        float acc = 0.f;
        #pragma unroll
        for (int k = 0; k < 16; k++) {
            int d = quarter*16 + k;
            acc += __shfl(hc, d) * w1[d*16 + jj];
        }
        acc += __shfl_xor(acc, 16);
        acc += __shfl_xor(acc, 32);
        if (lane < 16) M1d[r*16 + lane] = dv * acc;
    }
}

// ---------------- GCN16 pass 1: U = M0 @ M1d (per channel) ----------------
__global__ __launch_bounds__(256) void k_g1a(
    const int* __restrict__ cnt, const int* __restrict__ ecol,
    const float4* __restrict__ ev4, const float* __restrict__ M1d,
    float* __restrict__ U2) {
    __shared__ float red[4][32];
    int r = blockIdx.x;
    int wv = threadIdx.x >> 6, lane = threadIdx.x & 63;
    int d = lane & 15, ch = (lane >> 4) & 1, ep = lane >> 5;
    int len = min(cnt[r], CAP), base = r*CAP;
    int q0 = (len*wv) >> 2, q1 = (len*(wv+1)) >> 2;
    float acc = 0.f;
    int j = q0;
    for (; j+2 <= q1; j += 2) {
        int jj = base + j + ep;
        int c = ecol[jj]; float4 e = ev4[jj];
        acc += (ch ? e.y : e.x) * M1d[c*16 + d];
    }
    if (j < q1 && ep == 0) {
        int c = ecol[base+j]; float4 e = ev4[base+j];
        acc += (ch ? e.y : e.x) * M1d[c*16 + d];
    }
    acc += __shfl_xor(acc, 32);
    if (lane < 32) red[wv][lane] = acc;
    __syncthreads();
    if (wv == 0 && lane < 32) {
        float s = red[0][lane]+red[1][lane]+red[2][lane]+red[3][lane];
        U2[r*32 + d*2 + ch] = s;
    }
}

// ---------------- GCN16 pass 2 fused: P = M1 @ U, h1 = relu, M2d = dinv*(h1@w2) ----------------
__global__ __launch_bounds__(256) void k_g1b(
    const int* __restrict__ cnt, const int* __restrict__ ecol,
    const float4* __restrict__ ev4, const float* __restrict__ U2,
    const float* __restrict__ M1d, const float* __restrict__ dinv,
    const float* __restrict__ b1, const float* __restrict__ w2,
    float* __restrict__ M2d) {
    __shared__ float red[4][32];
    int r = blockIdx.x;
    int wv = threadIdx.x >> 6, lane = threadIdx.x & 63;
    int d = lane & 15, ch = (lane >> 4) & 1, ep = lane >> 5;
    int len = min(cnt[r], CAP), base = r*CAP;
    int q0 = (len*wv) >> 2, q1 = (len*(wv+1)) >> 2;
    float acc = 0.f;
    int j = q0;
    for (; j+2 <= q1; j += 2) {
        int jj = base + j + ep;
        int c = ecol[jj]; float4 e = ev4[jj];
        acc += (ch ? e.w : e.z) * U2[c*32 + d*2 + ch];
    }
    if (j < q1 && ep == 0) {
        int c = ecol[base+j]; float4 e = ev4[base+j];
        acc += (ch ? e.w : e.z) * U2[c*32 + d*2 + ch];
    }
    acc += __shfl_xor(acc, 32);
    if (lane < 32) red[wv][lane] = acc;
    __syncthreads();
    if (wv == 0) {
        float Pv = red[0][lane&31]+red[1][lane&31]+red[2][lane&31]+red[3][lane&31];
        Pv += __shfl_xor(Pv, 16);
        float dv = dinv[r];
        float hv = fmaxf(dv*(Pv + M1d[r*16 + (lane&15)]) + b1[lane&15], 0.f);
        float m2 = 0.f;
        #pragma unroll
        for (int k = 0; k < 16; k++) m2 += __shfl(hv, k) * w2[k*64 + lane];
        M2d[r*64 + lane] = dv * m2;
    }
}

// ---------------- GCN64 pass 1: V = M0 @ M2d (shared x, both ch) ----------------
__global__ __launch_bounds__(256) void k_g2a(
    const int* __restrict__ cnt, const int* __restrict__ ecol,
    const float4* __restrict__ ev4, const float* __restrict__ M2d,
    float2* __restrict__ V2) {
    __shared__ float redA[4][64], redP[4][64];
    int r = blockIdx.x;
    int wv = threadIdx.x >> 6, lane = threadIdx.x & 63;
    int len = min(cnt[r], CAP), base = r*CAP;
    int q0 = (len*wv) >> 2, q1 = (len*(wv+1)) >> 2;
    float a0=0.f,a1=0.f,p0=0.f,p1=0.f;
    int j = q0;
    for (; j+2 <= q1; j += 2) {
        int cA = ecol[base+j], cB = ecol[base+j+1];
        float4 eA = ev4[base+j], eB = ev4[base+j+1];
        float xA = M2d[cA*64+lane], xB = M2d[cB*64+lane];
        a0 += eA.x*xA; p0 += eA.y*xA;
        a1 += eB.x*xB; p1 += eB.y*xB;
    }
    if (j < q1) {
        int cA = ecol[base+j]; float4 eA = ev4[base+j];
        float xA = M2d[cA*64+lane];
        a0 += eA.x*xA; p0 += eA.y*xA;
    }
    redA[wv][lane] = a0+a1; redP[wv][lane] = p0+p1;
    __syncthreads();
    if (wv == 0) {
        float A = redA[0][lane]+redA[1][lane]+redA[2][lane]+redA[3][lane];
        float P = redP[0][lane]+redP[1][lane]+redP[2][lane]+redP[3][lane];
        V2[r*64 + lane] = make_float2(A, P);
    }
}

// ---------------- GCN64 pass 2 fused: R = M1 @ V, log_softmax, head for matching targets ----------------
__global__ __launch_bounds__(256) void k_g2b(
    const int* __restrict__ cnt, const int* __restrict__ ecol,
    const float4* __restrict__ ev4, const float2* __restrict__ V2,
    const float* __restrict__ M2d, const float* __restrict__ dinv,
    const float* __restrict__ b2, const int* __restrict__ tgt,
    const float* __restrict__ lin_w, const float* __restrict__ lin_b,
    float* __restrict__ out) {
    __shared__ float red[4][64];
    __shared__ float hsh[64];
    int r = blockIdx.x;
    int wv = threadIdx.x >> 6, lane = threadIdx.x & 63;
    int len = min(cnt[r], CAP), base = r*CAP;
    int q0 = (len*wv) >> 2, q1 = (len*(wv+1)) >> 2;
    float a0=0.f, a1=0.f;
    int j = q0;
    for (; j+2 <= q1; j += 2) {
        int cA = ecol[base+j], cB = ecol[base+j+1];
        float4 eA = ev4[base+j], eB = ev4[base+j+1];
        float2 xA = V2[cA*64+lane], xB = V2[cB*64+lane];
        a0 += eA.z*xA.x + eA.w*xA.y;
        a1 += eB.z*xB.x + eB.w*xB.y;
    }
    if (j < q1) {
        int cA = ecol[base+j]; float4 eA = ev4[base+j];
        float2 xA = V2[cA*64+lane];
        a0 += eA.z*xA.x + eA.w*xA.y;
    }
    red[wv][lane] = a0+a1;
    __syncthreads();
    if (wv == 0) {
        float S = red[0][lane]+red[1][lane]+red[2][lane]+red[3][lane];
        float v = dinv[r]*(S + M2d[r*64 + lane]) + b2[lane];
        float mx = v;
        #pragma unroll
        for (int o = 1; o < 64; o <<= 1) mx = fmaxf(mx, __shfl_xor(mx, o));
        float s = expf(v - mx);
        #pragma unroll
        for (int o = 1; o < 64; o <<= 1) s += __shfl_xor(s, o);
        hsh[lane] = v - mx - logf(s);
    }
    __syncthreads();
    // head: each thread scans 2 targets; write out rows whose target node == r
    for (int i = threadIdx.x; i < NTGT; i += 256) {
        if (tgt[i] == r) {
            #pragma unroll 4
            for (int k = 0; k < 16; k++) {
                float acc = 0.f;
                #pragma unroll
                for (int dd = 0; dd < 64; dd++) acc += hsh[dd] * lin_w[dd*16 + k];
                out[i*16 + k] = acc + lin_b[k];
            }
        }
    }
}

// ---------------- launch ----------------
extern "C" void kernel_launch(void* const* d_in, const int* in_sizes, int n_in,
                              void* d_out, int out_size, void* d_ws, size_t ws_size,
                              hipStream_t stream) {
    const float* X          = (const float*)d_in[0];
    const float* edge_value = (const float*)d_in[1];
    const float* conv_w     = (const float*)d_in[2];
    const float* Ws         = (const float*)d_in[3];
    const float* w1         = (const float*)d_in[4];
    const float* b1         = (const float*)d_in[5];
    const float* w2         = (const float*)d_in[6];
    const float* b2         = (const float*)d_in[7];
    const float* lin_w      = (const float*)d_in[8];
    const float* lin_b      = (const float*)d_in[9];
    const int*   ei         = (const int*)d_in[10];
    const int*   tgt        = (const int*)d_in[11];
    float* out = (float*)d_out;

    float* ws = (float*)d_ws;
    int*    cnt  = (int*)(ws + OFF_CNT);
    int*    ecol = (int*)(ws + OFF_ECOL);
    float4* ev4  = (float4*)(ws + OFF_EV);
    float2* Xp2  = (float2*)(ws + OFF_XP);
    float2* H12  = (float2*)(ws + OFF_H1);
    float2* s02  = (float2*)(ws + OFF_S0);
    float*  dinv = ws + OFF_DINV;
    float*  M1d  = ws + OFF_M1D;
    float*  U2   = ws + OFF_U;
    float*  M2d  = ws + OFF_M2D;
    float2* V2   = (float2*)(ws + OFF_V);

    hipMemsetAsync(cnt, 0, N_NODES*sizeof(int), stream);
    k_init<<<192, 256, 0, stream>>>(conv_w, X, Ws, ei, edge_value, cnt, ecol, ev4, Xp2);
    k_h0  <<<N_NODES, 256, 0, stream>>>(cnt, ecol, ev4, Xp2, H12, s02);
    k_h1  <<<N_NODES, 256, 0, stream>>>(cnt, ecol, ev4, H12, s02, Xp2, w1, dinv, M1d);
    k_g1a <<<N_NODES, 256, 0, stream>>>(cnt, ecol, ev4, M1d, U2);
    k_g1b <<<N_NODES, 256, 0, stream>>>(cnt, ecol, ev4, U2, M1d, dinv, b1, w2, M2d);
    k_g2a <<<N_NODES, 256, 0, stream>>>(cnt, ecol, ev4, M2d, V2);
    k_g2b <<<N_NODES, 256, 0, stream>>>(cnt, ecol, ev4, V2, M2d, dinv, b2, tgt, lin_w, lin_b, out);
}